// Round 12
// baseline (269.861 us; speedup 1.0000x reference)
//
#include <hip/hip_runtime.h>
#include <math.h>

#define D_MODEL 512
#define SEQ     1024
#define BATCH   4
#define N_LAYERS 2
#define N_HEAD  8
#define D_HEAD  64
#define D_INNER 1024
#define NTOK    (BATCH*SEQ)   // 4096
#define LN_EPS  1e-3f

typedef float f32x4 __attribute__((ext_vector_type(4)));
typedef short bf16x8 __attribute__((ext_vector_type(8)));
typedef unsigned short ushort_t;
typedef unsigned int uint_t;
typedef unsigned long long ull_t;

// fp32 -> bf16 round-to-nearest-even
__device__ inline ushort_t f2bf(float f) {
    uint_t u = __float_as_uint(f);
    u += 0x7FFFu + ((u >> 16) & 1u);
    return (ushort_t)(u >> 16);
}
__device__ inline float bf2f(ushort_t h) {
    return __uint_as_float((uint_t)h << 16);
}

// async global->LDS, 16B per lane (wave-uniform LDS base + lane*16)
__device__ __forceinline__ void gload16(const ushort_t* g, ushort_t* l) {
    __builtin_amdgcn_global_load_lds(
        (const __attribute__((address_space(1))) void*)g,
        (__attribute__((address_space(3))) void*)l, 16, 0, 0);
}

// ---------------------------------------------------------------- fused prep
#define PREP_E0 (NTOK * D_MODEL)                  // 2,097,152
#define PREP_E1 (1536 * 512)                      // 786,432
#define PREP_EW (N_LAYERS * D_INNER * D_MODEL)    // 1,048,576
#define PREP_TOTAL (PREP_E0 + 2 * PREP_E1 + 2 * PREP_EW)

__global__ void prep_kernel(const float* __restrict__ x,
                            const float* __restrict__ pe,
                            const float* __restrict__ w_qs,
                            const float* __restrict__ w_ks,
                            const float* __restrict__ w_vs,
                            const float* __restrict__ w1,
                            const float* __restrict__ w2,
                            float* __restrict__ X,
                            ushort_t* __restrict__ Xraw,
                            ushort_t* __restrict__ Wqkv,
                            ushort_t* __restrict__ WqkvL,
                            ushort_t* __restrict__ W1b,
                            ushort_t* __restrict__ W2b) {
    int idx = blockIdx.x * 256 + threadIdx.x;
    if (idx < PREP_E0) {
        int l = (idx / D_MODEL) % SEQ;
        int d = idx % D_MODEL;
        float xv = x[idx];
        X[idx] = xv + pe[l * D_MODEL + d];
        Xraw[idx] = f2bf(xv);
        return;
    }
    idx -= PREP_E0;
    if (idx < 2 * PREP_E1) {
        int layer = idx / PREP_E1;
        int j = idx - layer * PREP_E1;
        int n = j >> 9, k = j & 511;
        int which = n >> 9, h = (n >> 6) & 7, d = n & 63;
        size_t wofs = (size_t)layer * N_HEAD * D_MODEL * D_HEAD;
        const float* W = (which == 0) ? w_qs + wofs
                       : (which == 1) ? w_ks + wofs : w_vs + wofs;
        float v = W[((size_t)h * D_MODEL + k) * D_HEAD + d];
        ushort_t hv = f2bf(v);
        Wqkv[(size_t)layer * PREP_E1 + j] = hv;
        if (layer == 0) WqkvL[j] = f2bf(v - bf2f(hv));
        return;
    }
    idx -= 2 * PREP_E1;
    if (idx < PREP_EW) { W1b[idx] = f2bf(w1[idx]); return; }
    idx -= PREP_EW;
    W2b[idx] = f2bf(w2[idx]);
}

// ---------------------------------------------------------------- QKV scatter
__device__ inline void qkv_scatter(f32x4 a, int n, int m_base,
                                   const float* __restrict__ pew,
                                   ushort_t* Qhi, ushort_t* Qlo,
                                   ushort_t* Khi, ushort_t* Klo,
                                   ushort_t* Vt) {
    int which = n >> 9, hd = n & 511;
    int head = hd >> 6, d = hd & 63;
    int hb = head * BATCH + (m_base >> 10);
    int l  = m_base & 1023;
    if (pew) {
#pragma unroll
        for (int r = 0; r < 4; r++) a[r] += pew[(size_t)(l + r) * 1536 + n];
    }
    if (which == 2) {
        ushort4 pk = make_ushort4(f2bf(a[0]), f2bf(a[1]), f2bf(a[2]), f2bf(a[3]));
        *(ushort4*)(Vt + ((size_t)hb * D_HEAD + d) * SEQ + l) = pk;
    } else {
        ushort_t* H = (which == 0) ? Qhi : Khi;
        ushort_t* L = (which == 0) ? Qlo : Klo;
#pragma unroll
        for (int r = 0; r < 4; r++) {
            float v = a[r];
            ushort_t hv = f2bf(v);
            size_t off = ((size_t)hb * SEQ + l + r) * D_HEAD + d;
            H[off] = hv;
            L[off] = f2bf(v - bf2f(hv));
        }
    }
}

// ---------------------------------------------------------------- MFMA GEMM
// R7 tiles (validated): 128x64 for QKV (768 = 3/CU) and FFN1 (512 = 2/CU);
// FFN2 64^2 single-pass. BK=128; gload_lds width-16 + both-sides XOR swizzle.
template<int MODE, int TM, int TN>
__global__ __launch_bounds__(256, (TM == 128 ? 3 : 4))
void gemm_kernel(const ushort_t* __restrict__ A, const ushort_t* __restrict__ Bt,
                 const float* __restrict__ bias, const float* __restrict__ pew,
                 float* __restrict__ outF, ushort_t* __restrict__ outB,
                 ushort_t* __restrict__ Qhi, ushort_t* __restrict__ Qlo,
                 ushort_t* __restrict__ Khi, ushort_t* __restrict__ Klo,
                 ushort_t* __restrict__ Vt,
                 int M, int N, int K) {
    constexpr int BK = 128;
    constexpr int WM = TM / 2, WN = TN / 2;    // wave tile
    constexpr int MT = WM / 16, NT = WN / 16;  // frags per wave
    constexpr int WA = TM / 16;                // gload windows/wave (A): 1KB each
    constexpr int WB = TN / 16;
    __shared__ ushort_t As[TM * BK];   // TM=128: 32 KB; TM=64: 16 KB
    __shared__ ushort_t Bs[TN * BK];   // 16 KB
    const int tid = threadIdx.x;
    const int m0 = blockIdx.y * TM, n0 = blockIdx.x * TN;
    const int w = tid >> 6, lane = tid & 63;
    const int wr = w >> 1, wc = w & 1;
    const int col = lane & 15, quad = lane >> 4;
    const int srow = lane >> 4;        // staging: sub-row 0..3 within 4-row window
    const int scc  = lane & 15;        // staging: chunk 0..15

    f32x4 acc[MT][NT] = {};

    for (int k0 = 0; k0 < K; k0 += BK) {
        __syncthreads();
#pragma unroll
        for (int q = 0; q < WA; q++) {
            int row = (w * WA + q) * 4 + srow;
            int sch = scc ^ (row & 7);                  // inverse-swizzled src
            gload16(A + (size_t)(m0 + row) * K + k0 + sch * 8,
                    &As[(w * WA + q) * 4 * BK]);
        }
#pragma unroll
        for (int q = 0; q < WB; q++) {
            int row = (w * WB + q) * 4 + srow;
            int sch = scc ^ (row & 7);
            gload16(Bt + (size_t)(n0 + row) * K + k0 + sch * 8,
                    &Bs[(w * WB + q) * 4 * BK]);
        }
        __syncthreads();
#pragma unroll
        for (int ks = 0; ks < BK; ks += 32) {
            const int cb = ks >> 3;                     // chunk base 0,4,8,12
            const int sc_ = ((cb + quad) ^ (col & 7)) * 8;
            bf16x8 af[MT], bfr[NT];
#pragma unroll
            for (int t = 0; t < MT; t++)
                af[t] = *(const bf16x8*)(&As[(wr * WM + t * 16 + col) * BK + sc_]);
#pragma unroll
            for (int t = 0; t < NT; t++)
                bfr[t] = *(const bf16x8*)(&Bs[(wc * WN + t * 16 + col) * BK + sc_]);
#pragma unroll
            for (int mt = 0; mt < MT; mt++)
#pragma unroll
                for (int nt = 0; nt < NT; nt++)
                    acc[mt][nt] = __builtin_amdgcn_mfma_f32_16x16x32_bf16(
                        af[mt], bfr[nt], acc[mt][nt], 0, 0, 0);
        }
    }

#pragma unroll
    for (int mt = 0; mt < MT; mt++) {
#pragma unroll
        for (int nt = 0; nt < NT; nt++) {
            int n = n0 + wc * WN + nt * 16 + col;
            int m_base = m0 + wr * WM + mt * 16 + quad * 4;
            if (MODE == 0) {
                qkv_scatter(acc[mt][nt], n, m_base, pew, Qhi, Qlo, Khi, Klo, Vt);
            } else {
#pragma unroll
                for (int r = 0; r < 4; r++) {
                    int m = m_base + r;
                    float v = acc[mt][nt][r];
                    if (MODE == 1) {
                        float t = fmaxf(v + bias[n], 0.f);
                        outB[(size_t)m * N + n] = f2bf(t);
                    } else {
                        outF[(size_t)m * N + n] = v + bias[n];
                    }
                }
            }
        }
    }
}

// ---------------------------------------------------------------- hi/lo GEMM
__global__ __launch_bounds__(256, 4)
void gemm_hilo_kernel(const float* __restrict__ A,
                      const ushort_t* __restrict__ Bh,
                      const ushort_t* __restrict__ Bl,
                      float* __restrict__ outF, int M, int N, int K) {
    __shared__ ushort_t Ash[64][72];
    __shared__ ushort_t Asl[64][72];
    __shared__ ushort_t Bsh[64][72];
    __shared__ ushort_t Bsl[64][72];
    const int tid = threadIdx.x;
    const int m0 = blockIdx.y * 64, n0 = blockIdx.x * 64;
    const int w = tid >> 6, lane = tid & 63;
    const int wm = (w >> 1) * 32, wn = (w & 1) * 32;
    const int col = lane & 15, quad = lane >> 4;

    f32x4 acc[2][2] = {};

    for (int k0 = 0; k0 < K; k0 += 64) {
        __syncthreads();
#pragma unroll
        for (int p = 0; p < 4; p++) {
            int idx = p * 256 + tid;
            int row = idx >> 4, c4 = (idx & 15) * 4;
            float4 v = *(const float4*)(A + (size_t)(m0 + row) * K + k0 + c4);
            ushort_t h0 = f2bf(v.x), h1 = f2bf(v.y), h2 = f2bf(v.z), h3 = f2bf(v.w);
            *(ushort4*)(&Ash[row][c4]) = make_ushort4(h0, h1, h2, h3);
            *(ushort4*)(&Asl[row][c4]) = make_ushort4(
                f2bf(v.x - bf2f(h0)), f2bf(v.y - bf2f(h1)),
                f2bf(v.z - bf2f(h2)), f2bf(v.w - bf2f(h3)));
        }
#pragma unroll
        for (int p = 0; p < 2; p++) {
            int idx = p * 256 + tid;
            int row = idx >> 3, ch = (idx & 7) * 8;
            *(uint4*)(&Bsh[row][ch]) =
                *(const uint4*)(Bh + (size_t)(n0 + row) * K + k0 + ch);
            *(uint4*)(&Bsl[row][ch]) =
                *(const uint4*)(Bl + (size_t)(n0 + row) * K + k0 + ch);
        }
        __syncthreads();
#pragma unroll
        for (int ks = 0; ks < 64; ks += 32) {
            bf16x8 ah[2], al[2], bh[2], bl[2];
#pragma unroll
            for (int t = 0; t < 2; t++) {
                ah[t] = *(const bf16x8*)(&Ash[wm + t * 16 + col][ks + quad * 8]);
                al[t] = *(const bf16x8*)(&Asl[wm + t * 16 + col][ks + quad * 8]);
                bh[t] = *(const bf16x8*)(&Bsh[wn + t * 16 + col][ks + quad * 8]);
                bl[t] = *(const bf16x8*)(&Bsl[wn + t * 16 + col][ks + quad * 8]);
            }
#pragma unroll
            for (int mt = 0; mt < 2; mt++)
#pragma unroll
                for (int nt = 0; nt < 2; nt++) {
                    acc[mt][nt] = __builtin_amdgcn_mfma_f32_16x16x32_bf16(
                        ah[mt], bh[nt], acc[mt][nt], 0, 0, 0);
                    acc[mt][nt] = __builtin_amdgcn_mfma_f32_16x16x32_bf16(
                        ah[mt], bl[nt], acc[mt][nt], 0, 0, 0);
                    acc[mt][nt] = __builtin_amdgcn_mfma_f32_16x16x32_bf16(
                        al[mt], bh[nt], acc[mt][nt], 0, 0, 0);
                }
        }
    }

#pragma unroll
    for (int mt = 0; mt < 2; mt++)
#pragma unroll
        for (int nt = 0; nt < 2; nt++) {
            int n = n0 + wn + nt * 16 + col;
#pragma unroll
            for (int r = 0; r < 4; r++) {
                int m = m0 + wm + mt * 16 + quad * 4 + r;
                outF[(size_t)m * N + n] = acc[mt][nt][r];
            }
        }
}

// ---------------------------------------------------------------- attention
// R12: LDS diet via sequential-u softmax+PV — Pl [4][2][16][72] -> [4][16][72]
// (18->9 KB). LDS: HILO 72->63 KB (2/CU unchanged); non-HILO 54->45 KB ->
// 3 blocks/CU with __launch_bounds__(256,3) (VGPR cap 168; non-HILO state
// ~140). Pl reuse across u is safe: same-wave LDS FIFO + per-u fence; no
// cross-wave sharing (indexed by w). Keeps R11: dbuf 1-barrier/tile, T13
// defer-max, T14 issue-early, swapped QK^T, split-2 flash-decoding.
template<bool HILO>
__global__ __launch_bounds__(256, (HILO ? 2 : 3))
void attention_kernel(const ushort_t* __restrict__ Qhi,
                      const ushort_t* __restrict__ Qlo,
                      const ushort_t* __restrict__ Khi,
                      const ushort_t* __restrict__ Klo,
                      const ushort_t* __restrict__ Vt,
                      float* __restrict__ P0,
                      float* __restrict__ P1,
                      float2* __restrict__ ML) {
    const int bid = blockIdx.x;          // 512 = 2 splits x 256
    const int split = bid >> 8;
    const int r8  = bid & 255;
    const int j   = r8 >> 3;                   // 0..31
    const int hb  = (r8 & 7) * 4 + (j >> 3);   // bid&7 -> XCD-local hb group
    const int qp2 = j & 7;                     // 8 q-blocks of 128 rows
    const int h = hb >> 2, b = hb & 3;
    const int tid = threadIdx.x;
    const int w = tid >> 6, lane = tid & 63;
    const int col = lane & 15, quad = lane >> 4;
    const size_t kbase = (size_t)hb * SEQ * D_HEAD;
    const size_t vbase = (size_t)hb * D_HEAD * SEQ;

    __shared__ ushort_t Kh[2][64][72];               // 18 KB
    __shared__ ushort_t Kl[HILO ? 2 : 1][64][72];    // 18 KB when HILO
    __shared__ ushort_t Vs[2][64][72];               // 18 KB
    __shared__ ushort_t Pl[4][16][72];               // per-wave P^T, 9 KB

    const int srow0 = tid >> 3;                  // rows 0..31
    const int srow1 = 32 + (tid >> 3);           // rows 32..63
    const int sch   = (tid & 7) * 8;

    // Q fragments: 2 subtiles per wave (rows qbase + u*16 + col)
    const int qbase = qp2 * 128 + w * 32;
    bf16x8 qh[2][2], ql[2][2];
#pragma unroll
    for (int u = 0; u < 2; u++) {
        const ushort_t* qp = Qhi + kbase + (size_t)(qbase + u * 16 + col) * D_HEAD;
        qh[u][0] = *(const bf16x8*)(qp + quad * 8);
        qh[u][1] = *(const bf16x8*)(qp + 32 + quad * 8);
        if (HILO) {
            const ushort_t* lp = Qlo + kbase + (size_t)(qbase + u * 16 + col) * D_HEAD;
            ql[u][0] = *(const bf16x8*)(lp + quad * 8);
            ql[u][1] = *(const bf16x8*)(lp + 32 + quad * 8);
        }
    }

    f32x4 acco[2][4] = {};
    float mrun[2] = {-1e30f, -1e30f}, lrun[2] = {0.f, 0.f};
    const float inv_temper = 0.04419417382415922f;  // 1/sqrt(512)

    const int tbeg = split * (SEQ / 2);
    const int tend = tbeg + SEQ / 2;

    // T14 stage registers; prologue: tile0 -> buf0, then issue tile1 loads
    uint4 rK0, rK1, rL0, rL1, rV0, rV1;
    {
        const int t0 = tbeg;
        rK0 = *(const uint4*)(Khi + kbase + (size_t)(t0 + srow0) * D_HEAD + sch);
        rK1 = *(const uint4*)(Khi + kbase + (size_t)(t0 + srow1) * D_HEAD + sch);
        if (HILO) {
            rL0 = *(const uint4*)(Klo + kbase + (size_t)(t0 + srow0) * D_HEAD + sch);
            rL1 = *(const uint4*)(Klo + kbase + (size_t)(t0 + srow1) * D_HEAD + sch);
        }
        rV0 = *(const uint4*)(Vt + vbase + (size_t)srow0 * SEQ + t0 + sch);
        rV1 = *(const uint4*)(Vt + vbase + (size_t)srow1 * SEQ + t0 + sch);
        *(uint4*)(&Kh[0][srow0][sch]) = rK0;
        *(uint4*)(&Kh[0][srow1][sch]) = rK1;
        if (HILO) {
            *(uint4*)(&Kl[0][srow0][sch]) = rL0;
            *(uint4*)(&Kl[0][srow1][sch]) = rL1;
        }
        *(uint4*)(&Vs[0][srow0][sch]) = rV0;
        *(uint4*)(&Vs[0][srow1][sch]) = rV1;
    }
    __syncthreads();
    if (tbeg + 64 < tend) {
        const int tn = tbeg + 64;
        rK0 = *(const uint4*)(Khi + kbase + (size_t)(tn + srow0) * D_HEAD + sch);
        rK1 = *(const uint4*)(Khi + kbase + (size_t)(tn + srow1) * D_HEAD + sch);
        if (HILO) {
            rL0 = *(const uint4*)(Klo + kbase + (size_t)(tn + srow0) * D_HEAD + sch);
            rL1 = *(const uint4*)(Klo + kbase + (size_t)(tn + srow1) * D_HEAD + sch);
        }
        rV0 = *(const uint4*)(Vt + vbase + (size_t)srow0 * SEQ + tn + sch);
        rV1 = *(const uint4*)(Vt + vbase + (size_t)srow1 * SEQ + tn + sch);
    }

    int cur = 0;
    for (int t0 = tbeg; t0 < tend; t0 += 64) {
        // ---- S^T tiles from buf[cur]
        float sc[2][4][4];
#pragma unroll
        for (int nt = 0; nt < 4; nt++) {
            bf16x8 kh0 = *(const bf16x8*)(&Kh[cur][nt * 16 + col][quad * 8]);
            bf16x8 kh1 = *(const bf16x8*)(&Kh[cur][nt * 16 + col][32 + quad * 8]);
            f32x4 s0 = {}, s1 = {};
            s0 = __builtin_amdgcn_mfma_f32_16x16x32_bf16(kh0, qh[0][0], s0, 0, 0, 0);
            s0 = __builtin_amdgcn_mfma_f32_16x16x32_bf16(kh1, qh[0][1], s0, 0, 0, 0);
            s1 = __builtin_amdgcn_mfma_f32_16x16x32_bf16(kh0, qh[1][0], s1, 0, 0, 0);
            s1 = __builtin_amdgcn_mfma_f32_16x16x32_bf16(kh1, qh[1][1], s1, 0, 0, 0);
            if (HILO) {
                bf16x8 kl0 = *(const bf16x8*)(&Kl[cur][nt * 16 + col][quad * 8]);
                bf16x8 kl1 = *(const bf16x8*)(&Kl[cur][nt * 16 + col][32 + quad * 8]);
                s0 = __builtin_amdgcn_mfma_f32_16x16x32_bf16(kl0, qh[0][0], s0, 0, 0, 0);
                s0 = __builtin_amdgcn_mfma_f32_16x16x32_bf16(kl1, qh[0][1], s0, 0, 0, 0);
                s0 = __builtin_amdgcn_mfma_f32_16x16x32_bf16(kh0, ql[0][0], s0, 0, 0, 0);
                s0 = __builtin_amdgcn_mfma_f32_16x16x32_bf16(kh1, ql[0][1], s0, 0, 0, 0);
                s1 = __builtin_amdgcn_mfma_f32_16x16x32_bf16(kl0, qh[1][0], s1, 0, 0, 0);
                s1 = __builtin_amdgcn_mfma_f32_16x16x32_bf16(kl1, qh[1][1], s1, 0, 0, 0);
                s1 = __builtin_amdgcn_mfma_f32_16x16x32_bf16(kh0, ql[1][0], s1, 0, 0, 0);
                s1 = __builtin_amdgcn_mfma_f32_16x16x32_bf16(kh1, ql[1][1], s1, 0, 0, 0);
            }
#pragma unroll
            for (int r = 0; r < 4; r++) {
                sc[0][nt][r] = s0[r] * inv_temper;
                sc[1][nt][r] = s1[r] * inv_temper;
            }
        }

        // ---- per subtile, sequentially: softmax (T13) -> Pl -> PV
#pragma unroll
        for (int u = 0; u < 2; u++) {
            float tmax = sc[u][0][0];
#pragma unroll
            for (int nt = 0; nt < 4; nt++)
#pragma unroll
                for (int r = 0; r < 4; r++) tmax = fmaxf(tmax, sc[u][nt][r]);
            tmax = fmaxf(tmax, __shfl_xor(tmax, 16, 64));
            tmax = fmaxf(tmax, __shfl_xor(tmax, 32, 64));

            if (!__all(tmax - mrun[u] <= 8.f)) {
                float mn = fmaxf(mrun[u], tmax);
                float alpha = __expf(mrun[u] - mn);
                mrun[u] = mn;
                lrun[u] *= alpha;
#pragma unroll
                for (int nt = 0; nt < 4; nt++)
#pragma unroll
                    for (int r = 0; r < 4; r++) acco[u][nt][r] *= alpha;
            }
            const float mn = mrun[u];
            float tsum = 0.f;
#pragma unroll
            for (int nt = 0; nt < 4; nt++) {
                float p0 = __expf(sc[u][nt][0] - mn);
                float p1 = __expf(sc[u][nt][1] - mn);
                float p2 = __expf(sc[u][nt][2] - mn);
                float p3 = __expf(sc[u][nt][3] - mn);
                tsum += (p0 + p1) + (p2 + p3);
                ull_t pk = (ull_t)f2bf(p0) | ((ull_t)f2bf(p1) << 16)
                         | ((ull_t)f2bf(p2) << 32) | ((ull_t)f2bf(p3) << 48);
                *(ull_t*)(&Pl[w][col][nt * 16 + quad * 4]) = pk;
            }
            tsum += __shfl_xor(tsum, 16, 64);
            tsum += __shfl_xor(tsum, 32, 64);
            lrun[u] += tsum;

            __threadfence_block();   // order the typed-punned P round-trip

            union { ulong2 uu; bf16x8 v; } pa0, pa1;
            pa0.uu = *(const ulong2*)(&Pl[w][col][quad * 8]);        // keys 0..31
            pa1.uu = *(const ulong2*)(&Pl[w][col][32 + quad * 8]);   // keys 32..63
#pragma unroll
            for (int nt = 0; nt < 4; nt++) {
                bf16x8 bv0 = *(const bf16x8*)(&Vs[cur][nt * 16 + col][quad * 8]);
                bf16x8 bv1 = *(const bf16x8*)(&Vs[cur][nt * 16 + col][32 + quad * 8]);
                acco[u][nt] = __builtin_amdgcn_mfma_f32_16x16x32_bf16(bv0, pa0.v, acco[u][nt], 0, 0, 0);
                acco[u][nt] = __builtin_amdgcn_mfma_f32_16x16x32_bf16(bv1, pa1.v, acco[u][nt], 0, 0, 0);
            }
        }

        // ---- stage tile t0+64 into buf[cur^1]; issue loads for t0+128
        if (t0 + 64 < tend) {
            *(uint4*)(&Kh[cur ^ 1][srow0][sch]) = rK0;
            *(uint4*)(&Kh[cur ^ 1][srow1][sch]) = rK1;
            if (HILO) {
                *(uint4*)(&Kl[cur ^ 1][srow0][sch]) = rL0;
                *(uint4*)(&Kl[cur ^ 1][srow1][sch]) = rL1;
            }
            *(uint4*)(&Vs[cur ^ 1][srow0][sch]) = rV0;
            *(uint4*)(&Vs[cur ^ 1][srow1][sch]) = rV1;
            if (t0 + 128 < tend) {
                const int tn = t0 + 128;
                rK0 = *(const uint4*)(Khi + kbase + (size_t)(tn + srow0) * D_HEAD + sch);
                rK1 = *(const uint4*)(Khi + kbase + (size_t)(tn + srow1) * D_HEAD + sch);
                if (HILO) {
                    rL0 = *(const uint4*)(Klo + kbase + (size_t)(tn + srow0) * D_HEAD + sch);
                    rL1 = *(const uint4*)(Klo + kbase + (size_t)(tn + srow1) * D_HEAD + sch);
                }
                rV0 = *(const uint4*)(Vt + vbase + (size_t)srow0 * SEQ + tn + sch);
                rV1 = *(const uint4*)(Vt + vbase + (size_t)srow1 * SEQ + tn + sch);
            }
        }
        __syncthreads();   // publishes buf[cur^1]; also closes reads of buf[cur]
        cur ^= 1;
    }

    // unnormalized partials + (m,l); combined in add_norm_combine_kernel
    float* dst = split ? P1 : P0;
#pragma unroll
    for (int u = 0; u < 2; u++) {
        const int qrow = qbase + u * 16 + col;
#pragma unroll
        for (int nt = 0; nt < 4; nt++)
            *(f32x4*)(&dst[((size_t)b * SEQ + qrow) * D_MODEL + h * D_HEAD
                           + nt * 16 + quad * 4]) = acco[u][nt];
        if (quad == 0)
            ML[((size_t)split * 32 + hb) * SEQ + qrow] = make_float2(mrun[u], lrun[u]);
    }
}

// ---------------------------------------------------------------- add + LN
// Wave-per-token LN (R9, validated): f32x4 loads, __shfl_xor reductions,
// zero barriers.
__device__ __forceinline__ float wave_sum_64(float v) {
#pragma unroll
    for (int off = 32; off > 0; off >>= 1) v += __shfl_xor(v, off, 64);
    return v;
}

__global__ void add_norm_kernel(const float* __restrict__ A,
                                const float* __restrict__ R,
                                const float* __restrict__ ga,
                                const float* __restrict__ gb,
                                float* __restrict__ Out,
                                ushort_t* __restrict__ OutBf) {
    int tok = blockIdx.x * 4 + (threadIdx.x >> 6);
    int lane = threadIdx.x & 63;
    size_t base = (size_t)tok * D_MODEL + lane * 8;
    f32x4 a0 = *(const f32x4*)(A + base);
    f32x4 a1 = *(const f32x4*)(A + base + 4);
    f32x4 r0 = *(const f32x4*)(R + base);
    f32x4 r1 = *(const f32x4*)(R + base + 4);
    f32x4 z0, z1;
#pragma unroll
    for (int t = 0; t < 4; t++) { z0[t] = a0[t] + r0[t]; z1[t] = a1[t] + r1[t]; }
    float s = (z0[0] + z0[1] + z0[2] + z0[3]) + (z1[0] + z1[1] + z1[2] + z1[3]);
    s = wave_sum_64(s);
    float mu = s * (1.f / (float)D_MODEL);
    float ss = 0.f;
#pragma unroll
    for (int t = 0; t < 4; t++) {
        float d0 = z0[t] - mu, d1 = z1[t] - mu;
        ss += d0 * d0 + d1 * d1;
    }
    ss = wave_sum_64(ss);
    float sigma = sqrtf(ss * (1.f / (float)(D_MODEL - 1)));
    float inv = 1.f / (sigma + LN_EPS);
    f32x4 g0 = *(const f32x4*)(ga + lane * 8);
    f32x4 g1 = *(const f32x4*)(ga + lane * 8 + 4);
    f32x4 h0 = *(const f32x4*)(gb + lane * 8);
    f32x4 h1 = *(const f32x4*)(gb + lane * 8 + 4);
    f32x4 o0, o1;
    bf16x8 pk;
#pragma unroll
    for (int t = 0; t < 4; t++) {
        o0[t] = (z0[t] - mu) * inv * g0[t] + h0[t];
        o1[t] = (z1[t] - mu) * inv * g1[t] + h1[t];
        pk[t] = (short)f2bf(o0[t]);
        pk[t + 4] = (short)f2bf(o1[t]);
    }
    *(f32x4*)(Out + base) = o0;
    *(f32x4*)(Out + base + 4) = o1;
    *(bf16x8*)(OutBf + base) = pk;
}

// Fuses the 2-way flash-decoding combine with residual-add + LN (ln1 path).
__global__ void add_norm_combine_kernel(const float* __restrict__ Pa,
                                        const float* __restrict__ Pb,
                                        const float2* __restrict__ ML,
                                        const float* __restrict__ R,
                                        const float* __restrict__ ga,
                                        const float* __restrict__ gb,
                                        float* __restrict__ Out,
                                        ushort_t* __restrict__ OutBf) {
    int tok = blockIdx.x * 4 + (threadIdx.x >> 6);
    int lane = threadIdx.x & 63;
    int b = tok >> 10, l = tok & 1023;
    int hb0 = (lane >> 3) * 4 + b;
    float2 u0 = ML[(size_t)hb0 * SEQ + l];
    float2 u1 = ML[(size_t)(32 + hb0) * SEQ + l];
    float M = fmaxf(u0.x, u1.x);
    float e0 = __expf(u0.x - M), e1 = __expf(u1.x - M);
    float sinv = 1.f / (e0 * u0.y + e1 * u1.y);
    float sa = e0 * sinv, sb = e1 * sinv;
    size_t base = (size_t)tok * D_MODEL + lane * 8;
    f32x4 pa0 = *(const f32x4*)(Pa + base);
    f32x4 pa1 = *(const f32x4*)(Pa + base + 4);
    f32x4 pb0 = *(const f32x4*)(Pb + base);
    f32x4 pb1 = *(const f32x4*)(Pb + base + 4);
    f32x4 r0 = *(const f32x4*)(R + base);
    f32x4 r1 = *(const f32x4*)(R + base + 4);
    f32x4 z0, z1;
#pragma unroll
    for (int t = 0; t < 4; t++) {
        z0[t] = pa0[t] * sa + pb0[t] * sb + r0[t];
        z1[t] = pa1[t] * sa + pb1[t] * sb + r1[t];
    }
    float s = (z0[0] + z0[1] + z0[2] + z0[3]) + (z1[0] + z1[1] + z1[2] + z1[3]);
    s = wave_sum_64(s);
    float mu = s * (1.f / (float)D_MODEL);
    float ss = 0.f;
#pragma unroll
    for (int t = 0; t < 4; t++) {
        float d0 = z0[t] - mu, d1 = z1[t] - mu;
        ss += d0 * d0 + d1 * d1;
    }
    ss = wave_sum_64(ss);
    float sigma = sqrtf(ss * (1.f / (float)(D_MODEL - 1)));
    float inv = 1.f / (sigma + LN_EPS);
    f32x4 g0 = *(const f32x4*)(ga + lane * 8);
    f32x4 g1 = *(const f32x4*)(ga + lane * 8 + 4);
    f32x4 h0 = *(const f32x4*)(gb + lane * 8);
    f32x4 h1 = *(const f32x4*)(gb + lane * 8 + 4);
    f32x4 o0, o1;
    bf16x8 pk;
#pragma unroll
    for (int t = 0; t < 4; t++) {
        o0[t] = (z0[t] - mu) * inv * g0[t] + h0[t];
        o1[t] = (z1[t] - mu) * inv * g1[t] + h1[t];
        pk[t] = (short)f2bf(o0[t]);
        pk[t + 4] = (short)f2bf(o1[t]);
    }
    *(f32x4*)(Out + base) = o0;
    *(f32x4*)(Out + base + 4) = o1;
    *(bf16x8*)(OutBf + base) = pk;
}

// ---------------------------------------------------------------- launch
extern "C" void kernel_launch(void* const* d_in, const int* in_sizes, int n_in,
                              void* d_out, int out_size, void* d_ws, size_t ws_size,
                              hipStream_t stream) {
    const float* x     = (const float*)d_in[0];
    const float* pe    = (const float*)d_in[1];
    const float* w_qs  = (const float*)d_in[2];
    const float* w_ks  = (const float*)d_in[3];
    const float* w_vs  = (const float*)d_in[4];
    const float* ln1_a = (const float*)d_in[5];
    const float* ln1_b = (const float*)d_in[6];
    const float* w1    = (const float*)d_in[7];
    const float* b1    = (const float*)d_in[8];
    const float* w2    = (const float*)d_in[9];
    const float* b2    = (const float*)d_in[10];
    const float* ln2_a = (const float*)d_in[11];
    const float* ln2_b = (const float*)d_in[12];
    float* out = (float*)d_out;

    const size_t NXD = (size_t)NTOK * D_MODEL;       // 2M elements
    char* p = (char*)d_ws;
    float*    X    = (float*)p;     p += NXD * 4;                 // 8 MB
    float*    Ob   = (float*)p;     p += NXD * 4;                 // 8 MB
    ushort_t* Xbf  = (ushort_t*)p;  p += NXD * 2;                 // 4 MB
    ushort_t* Xraw = (ushort_t*)p;  p += NXD * 2;                 // 4 MB  bf16(x)
    ushort_t* Qhi  = (ushort_t*)p;  p += NXD * 2;                 // 4 MB
    ushort_t* Qlo  = (ushort_t*)p;  p += NXD * 2;                 // 4 MB
    ushort_t* Khi  = (ushort_t*)p;  p += NXD * 2;                 // 4 MB
    ushort_t* Klo  = (ushort_t*)p;  p += NXD * 2;                 // 4 MB
    ushort_t* Vt   = (ushort_t*)p;  p += NXD * 2;                 // 4 MB
    ushort_t* Wqkv = (ushort_t*)p;  p += (size_t)N_LAYERS * 1536 * 512 * 2;  // 3 MB (hi)
    ushort_t* WqkvL= (ushort_t*)p;  p += (size_t)1536 * 512 * 2;  // 1.5 MB (lo, layer 0)
    ushort_t* W1b  = (ushort_t*)p;  p += (size_t)N_LAYERS * D_INNER * D_MODEL * 2;  // 2 MB
    ushort_t* W2b  = (ushort_t*)p;  p += (size_t)N_LAYERS * D_MODEL * D_INNER * 2;  // 2 MB
    float2*   ML   = (float2*)p;    /* 512 KB */
    // Aliases (stream-ordered safe): H = Qhi/Qlo (dead after attention);
    // PEW = Ob; attention partials: P0 = Ob, P1 = out (d_out).
    ushort_t* Hbf  = Qhi;
    float*    PEW  = Ob;

    prep_kernel<<<(PREP_TOTAL + 255) / 256, 256, 0, stream>>>(
        x, pe, w_qs, w_ks, w_vs, w1, w2, X, Xraw, Wqkv, WqkvL, W1b, W2b);

    for (int i = 0; i < N_LAYERS; i++) {
        if (i == 0) {
            gemm_hilo_kernel<<<dim3(1536 / 64, SEQ / 64), 256, 0, stream>>>(
                pe, Wqkv, WqkvL, PEW, SEQ, 1536, D_MODEL);
            gemm_kernel<0, 128, 64><<<dim3(1536 / 64, NTOK / 128), 256, 0, stream>>>(
                Xraw, Wqkv, nullptr, PEW, nullptr, nullptr,
                Qhi, Qlo, Khi, Klo, Vt, NTOK, 1536, D_MODEL);
            attention_kernel<true><<<512, 256, 0, stream>>>(
                Qhi, Qlo, Khi, Klo, Vt, Ob, out, ML);
        } else {
            gemm_kernel<0, 128, 64><<<dim3(1536 / 64, NTOK / 128), 256, 0, stream>>>(
                Xbf, Wqkv + (size_t)i * 1536 * 512, nullptr, nullptr, nullptr,
                nullptr, Qhi, Qlo, Khi, Klo, Vt, NTOK, 1536, D_MODEL);
            attention_kernel<false><<<512, 256, 0, stream>>>(
                Qhi, Qlo, Khi, Klo, Vt, Ob, out, ML);
        }

        add_norm_combine_kernel<<<NTOK / 4, 256, 0, stream>>>(
            Ob, out, ML, X, ln1_a + i * D_MODEL, ln1_b + i * D_MODEL, X, Xbf);

        // FFN1: M=4096, N=1024, K=512, bias+relu -> bf16 H (aliases Qhi/Qlo)
        gemm_kernel<1, 128, 64><<<dim3(D_INNER / 64, NTOK / 128), 256, 0, stream>>>(
            Xbf, W1b + (size_t)i * D_INNER * D_MODEL, b1 + (size_t)i * D_INNER,
            nullptr, nullptr, Hbf, nullptr, nullptr, nullptr, nullptr, nullptr,
            NTOK, D_INNER, D_MODEL);

        // FFN2: M=4096, N=512, K=1024, bias -> fp32 Ob (single-pass 64^2)
        gemm_kernel<2, 64, 64><<<dim3(D_MODEL / 64, NTOK / 64), 256, 0, stream>>>(
            Hbf, W2b + (size_t)i * D_MODEL * D_INNER, b2 + (size_t)i * D_MODEL,
            nullptr, Ob, nullptr, nullptr, nullptr, nullptr, nullptr, nullptr,
            NTOK, D_MODEL, D_INNER);

        float* dst = (i == N_LAYERS - 1) ? out : X;
        add_norm_kernel<<<NTOK / 4, 256, 0, stream>>>(
            Ob, X, ln2_a + i * D_MODEL, ln2_b + i * D_MODEL, dst, Xbf);
    }
}

// Round 13
// 263.068 us; speedup vs baseline: 1.0258x; 1.0258x over previous
//
#include <hip/hip_runtime.h>
#include <math.h>

#define D_MODEL 512
#define SEQ     1024
#define BATCH   4
#define N_LAYERS 2
#define N_HEAD  8
#define D_HEAD  64
#define D_INNER 1024
#define NTOK    (BATCH*SEQ)   // 4096
#define LN_EPS  1e-3f

typedef float f32x4 __attribute__((ext_vector_type(4)));
typedef short bf16x8 __attribute__((ext_vector_type(8)));
typedef unsigned short ushort_t;
typedef unsigned int uint_t;
typedef unsigned long long ull_t;

// fp32 -> bf16 round-to-nearest-even
__device__ inline ushort_t f2bf(float f) {
    uint_t u = __float_as_uint(f);
    u += 0x7FFFu + ((u >> 16) & 1u);
    return (ushort_t)(u >> 16);
}
__device__ inline float bf2f(ushort_t h) {
    return __uint_as_float((uint_t)h << 16);
}

// async global->LDS, 16B per lane (wave-uniform LDS base + lane*16)
__device__ __forceinline__ void gload16(const ushort_t* g, ushort_t* l) {
    __builtin_amdgcn_global_load_lds(
        (const __attribute__((address_space(1))) void*)g,
        (__attribute__((address_space(3))) void*)l, 16, 0, 0);
}

// ---------------------------------------------------------------- fused prep
#define PREP_E0 (NTOK * D_MODEL)                  // 2,097,152
#define PREP_E1 (1536 * 512)                      // 786,432
#define PREP_EW (N_LAYERS * D_INNER * D_MODEL)    // 1,048,576
#define PREP_TOTAL (PREP_E0 + 2 * PREP_E1 + 2 * PREP_EW)

__global__ void prep_kernel(const float* __restrict__ x,
                            const float* __restrict__ pe,
                            const float* __restrict__ w_qs,
                            const float* __restrict__ w_ks,
                            const float* __restrict__ w_vs,
                            const float* __restrict__ w1,
                            const float* __restrict__ w2,
                            float* __restrict__ X,
                            ushort_t* __restrict__ Xraw,
                            ushort_t* __restrict__ Wqkv,
                            ushort_t* __restrict__ WqkvL,
                            ushort_t* __restrict__ W1b,
                            ushort_t* __restrict__ W2b) {
    int idx = blockIdx.x * 256 + threadIdx.x;
    if (idx < PREP_E0) {
        int l = (idx / D_MODEL) % SEQ;
        int d = idx % D_MODEL;
        float xv = x[idx];
        X[idx] = xv + pe[l * D_MODEL + d];
        Xraw[idx] = f2bf(xv);
        return;
    }
    idx -= PREP_E0;
    if (idx < 2 * PREP_E1) {
        int layer = idx / PREP_E1;
        int j = idx - layer * PREP_E1;
        int n = j >> 9, k = j & 511;
        int which = n >> 9, h = (n >> 6) & 7, d = n & 63;
        size_t wofs = (size_t)layer * N_HEAD * D_MODEL * D_HEAD;
        const float* W = (which == 0) ? w_qs + wofs
                       : (which == 1) ? w_ks + wofs : w_vs + wofs;
        float v = W[((size_t)h * D_MODEL + k) * D_HEAD + d];
        ushort_t hv = f2bf(v);
        Wqkv[(size_t)layer * PREP_E1 + j] = hv;
        if (layer == 0) WqkvL[j] = f2bf(v - bf2f(hv));
        return;
    }
    idx -= 2 * PREP_E1;
    if (idx < PREP_EW) { W1b[idx] = f2bf(w1[idx]); return; }
    idx -= PREP_EW;
    W2b[idx] = f2bf(w2[idx]);
}

// ---------------------------------------------------------------- QKV scatter
__device__ inline void qkv_scatter(f32x4 a, int n, int m_base,
                                   const float* __restrict__ pew,
                                   ushort_t* Qhi, ushort_t* Qlo,
                                   ushort_t* Khi, ushort_t* Klo,
                                   ushort_t* Vt) {
    int which = n >> 9, hd = n & 511;
    int head = hd >> 6, d = hd & 63;
    int hb = head * BATCH + (m_base >> 10);
    int l  = m_base & 1023;
    if (pew) {
#pragma unroll
        for (int r = 0; r < 4; r++) a[r] += pew[(size_t)(l + r) * 1536 + n];
    }
    if (which == 2) {
        ushort4 pk = make_ushort4(f2bf(a[0]), f2bf(a[1]), f2bf(a[2]), f2bf(a[3]));
        *(ushort4*)(Vt + ((size_t)hb * D_HEAD + d) * SEQ + l) = pk;
    } else {
        ushort_t* H = (which == 0) ? Qhi : Khi;
        ushort_t* L = (which == 0) ? Qlo : Klo;
#pragma unroll
        for (int r = 0; r < 4; r++) {
            float v = a[r];
            ushort_t hv = f2bf(v);
            size_t off = ((size_t)hb * SEQ + l + r) * D_HEAD + d;
            H[off] = hv;
            L[off] = f2bf(v - bf2f(hv));
        }
    }
}

// ---------------------------------------------------------------- MFMA GEMM
// R7 tiles (validated): 128x64 for QKV (768 = 3/CU) and FFN1 (512 = 2/CU);
// FFN2 64^2 single-pass. BK=128; gload_lds width-16 + both-sides XOR swizzle.
template<int MODE, int TM, int TN>
__global__ __launch_bounds__(256, (TM == 128 ? 3 : 4))
void gemm_kernel(const ushort_t* __restrict__ A, const ushort_t* __restrict__ Bt,
                 const float* __restrict__ bias, const float* __restrict__ pew,
                 float* __restrict__ outF, ushort_t* __restrict__ outB,
                 ushort_t* __restrict__ Qhi, ushort_t* __restrict__ Qlo,
                 ushort_t* __restrict__ Khi, ushort_t* __restrict__ Klo,
                 ushort_t* __restrict__ Vt,
                 int M, int N, int K) {
    constexpr int BK = 128;
    constexpr int WM = TM / 2, WN = TN / 2;    // wave tile
    constexpr int MT = WM / 16, NT = WN / 16;  // frags per wave
    constexpr int WA = TM / 16;                // gload windows/wave (A): 1KB each
    constexpr int WB = TN / 16;
    __shared__ ushort_t As[TM * BK];   // TM=128: 32 KB; TM=64: 16 KB
    __shared__ ushort_t Bs[TN * BK];   // 16 KB
    const int tid = threadIdx.x;
    const int m0 = blockIdx.y * TM, n0 = blockIdx.x * TN;
    const int w = tid >> 6, lane = tid & 63;
    const int wr = w >> 1, wc = w & 1;
    const int col = lane & 15, quad = lane >> 4;
    const int srow = lane >> 4;        // staging: sub-row 0..3 within 4-row window
    const int scc  = lane & 15;        // staging: chunk 0..15

    f32x4 acc[MT][NT] = {};

    for (int k0 = 0; k0 < K; k0 += BK) {
        __syncthreads();
#pragma unroll
        for (int q = 0; q < WA; q++) {
            int row = (w * WA + q) * 4 + srow;
            int sch = scc ^ (row & 7);                  // inverse-swizzled src
            gload16(A + (size_t)(m0 + row) * K + k0 + sch * 8,
                    &As[(w * WA + q) * 4 * BK]);
        }
#pragma unroll
        for (int q = 0; q < WB; q++) {
            int row = (w * WB + q) * 4 + srow;
            int sch = scc ^ (row & 7);
            gload16(Bt + (size_t)(n0 + row) * K + k0 + sch * 8,
                    &Bs[(w * WB + q) * 4 * BK]);
        }
        __syncthreads();
#pragma unroll
        for (int ks = 0; ks < BK; ks += 32) {
            const int cb = ks >> 3;                     // chunk base 0,4,8,12
            const int sc_ = ((cb + quad) ^ (col & 7)) * 8;
            bf16x8 af[MT], bfr[NT];
#pragma unroll
            for (int t = 0; t < MT; t++)
                af[t] = *(const bf16x8*)(&As[(wr * WM + t * 16 + col) * BK + sc_]);
#pragma unroll
            for (int t = 0; t < NT; t++)
                bfr[t] = *(const bf16x8*)(&Bs[(wc * WN + t * 16 + col) * BK + sc_]);
#pragma unroll
            for (int mt = 0; mt < MT; mt++)
#pragma unroll
                for (int nt = 0; nt < NT; nt++)
                    acc[mt][nt] = __builtin_amdgcn_mfma_f32_16x16x32_bf16(
                        af[mt], bfr[nt], acc[mt][nt], 0, 0, 0);
        }
    }

#pragma unroll
    for (int mt = 0; mt < MT; mt++) {
#pragma unroll
        for (int nt = 0; nt < NT; nt++) {
            int n = n0 + wc * WN + nt * 16 + col;
            int m_base = m0 + wr * WM + mt * 16 + quad * 4;
            if (MODE == 0) {
                qkv_scatter(acc[mt][nt], n, m_base, pew, Qhi, Qlo, Khi, Klo, Vt);
            } else {
#pragma unroll
                for (int r = 0; r < 4; r++) {
                    int m = m_base + r;
                    float v = acc[mt][nt][r];
                    if (MODE == 1) {
                        float t = fmaxf(v + bias[n], 0.f);
                        outB[(size_t)m * N + n] = f2bf(t);
                    } else {
                        outF[(size_t)m * N + n] = v + bias[n];
                    }
                }
            }
        }
    }
}

// ---------------------------------------------------------------- hi/lo GEMM
__global__ __launch_bounds__(256, 4)
void gemm_hilo_kernel(const float* __restrict__ A,
                      const ushort_t* __restrict__ Bh,
                      const ushort_t* __restrict__ Bl,
                      float* __restrict__ outF, int M, int N, int K) {
    __shared__ ushort_t Ash[64][72];
    __shared__ ushort_t Asl[64][72];
    __shared__ ushort_t Bsh[64][72];
    __shared__ ushort_t Bsl[64][72];
    const int tid = threadIdx.x;
    const int m0 = blockIdx.y * 64, n0 = blockIdx.x * 64;
    const int w = tid >> 6, lane = tid & 63;
    const int wm = (w >> 1) * 32, wn = (w & 1) * 32;
    const int col = lane & 15, quad = lane >> 4;

    f32x4 acc[2][2] = {};

    for (int k0 = 0; k0 < K; k0 += 64) {
        __syncthreads();
#pragma unroll
        for (int p = 0; p < 4; p++) {
            int idx = p * 256 + tid;
            int row = idx >> 4, c4 = (idx & 15) * 4;
            float4 v = *(const float4*)(A + (size_t)(m0 + row) * K + k0 + c4);
            ushort_t h0 = f2bf(v.x), h1 = f2bf(v.y), h2 = f2bf(v.z), h3 = f2bf(v.w);
            *(ushort4*)(&Ash[row][c4]) = make_ushort4(h0, h1, h2, h3);
            *(ushort4*)(&Asl[row][c4]) = make_ushort4(
                f2bf(v.x - bf2f(h0)), f2bf(v.y - bf2f(h1)),
                f2bf(v.z - bf2f(h2)), f2bf(v.w - bf2f(h3)));
        }
#pragma unroll
        for (int p = 0; p < 2; p++) {
            int idx = p * 256 + tid;
            int row = idx >> 3, ch = (idx & 7) * 8;
            *(uint4*)(&Bsh[row][ch]) =
                *(const uint4*)(Bh + (size_t)(n0 + row) * K + k0 + ch);
            *(uint4*)(&Bsl[row][ch]) =
                *(const uint4*)(Bl + (size_t)(n0 + row) * K + k0 + ch);
        }
        __syncthreads();
#pragma unroll
        for (int ks = 0; ks < 64; ks += 32) {
            bf16x8 ah[2], al[2], bh[2], bl[2];
#pragma unroll
            for (int t = 0; t < 2; t++) {
                ah[t] = *(const bf16x8*)(&Ash[wm + t * 16 + col][ks + quad * 8]);
                al[t] = *(const bf16x8*)(&Asl[wm + t * 16 + col][ks + quad * 8]);
                bh[t] = *(const bf16x8*)(&Bsh[wn + t * 16 + col][ks + quad * 8]);
                bl[t] = *(const bf16x8*)(&Bsl[wn + t * 16 + col][ks + quad * 8]);
            }
#pragma unroll
            for (int mt = 0; mt < 2; mt++)
#pragma unroll
                for (int nt = 0; nt < 2; nt++) {
                    acc[mt][nt] = __builtin_amdgcn_mfma_f32_16x16x32_bf16(
                        ah[mt], bh[nt], acc[mt][nt], 0, 0, 0);
                    acc[mt][nt] = __builtin_amdgcn_mfma_f32_16x16x32_bf16(
                        ah[mt], bl[nt], acc[mt][nt], 0, 0, 0);
                    acc[mt][nt] = __builtin_amdgcn_mfma_f32_16x16x32_bf16(
                        al[mt], bh[nt], acc[mt][nt], 0, 0, 0);
                }
        }
    }

#pragma unroll
    for (int mt = 0; mt < 2; mt++)
#pragma unroll
        for (int nt = 0; nt < 2; nt++) {
            int n = n0 + wn + nt * 16 + col;
#pragma unroll
            for (int r = 0; r < 4; r++) {
                int m = m0 + wm + mt * 16 + quad * 4 + r;
                outF[(size_t)m * N + n] = acc[mt][nt][r];
            }
        }
}

// ---------------------------------------------------------------- attention
// R11 config (best measured, 265.6): dbuf 1-barrier/tile, PARALLEL-u softmax
// (u=0/u=1 chains interleave and hide each other's shuffle/exp latency —
// R12's sequential-u regressed), T13 defer-max (THR=8), T14 issue-early regs,
// swapped QK^T scalar-m/l, split-2 flash-decoding. 72 KB LDS (HILO), 2/CU.
template<bool HILO>
__global__ __launch_bounds__(256, 2)
void attention_kernel(const ushort_t* __restrict__ Qhi,
                      const ushort_t* __restrict__ Qlo,
                      const ushort_t* __restrict__ Khi,
                      const ushort_t* __restrict__ Klo,
                      const ushort_t* __restrict__ Vt,
                      float* __restrict__ P0,
                      float* __restrict__ P1,
                      float2* __restrict__ ML) {
    const int bid = blockIdx.x;          // 512 = 2 splits x 256
    const int split = bid >> 8;
    const int r8  = bid & 255;
    const int j   = r8 >> 3;                   // 0..31
    const int hb  = (r8 & 7) * 4 + (j >> 3);   // bid&7 -> XCD-local hb group
    const int qp2 = j & 7;                     // 8 q-blocks of 128 rows
    const int h = hb >> 2, b = hb & 3;
    const int tid = threadIdx.x;
    const int w = tid >> 6, lane = tid & 63;
    const int col = lane & 15, quad = lane >> 4;
    const size_t kbase = (size_t)hb * SEQ * D_HEAD;
    const size_t vbase = (size_t)hb * D_HEAD * SEQ;

    __shared__ ushort_t Kh[2][64][72];               // 18 KB
    __shared__ ushort_t Kl[HILO ? 2 : 1][64][72];    // 18 KB when HILO
    __shared__ ushort_t Vs[2][64][72];               // 18 KB
    __shared__ ushort_t Pl[4][2][16][72];            // per-wave P^T, 18 KB

    const int srow0 = tid >> 3;                  // rows 0..31
    const int srow1 = 32 + (tid >> 3);           // rows 32..63
    const int sch   = (tid & 7) * 8;

    // Q fragments: 2 subtiles per wave (rows qbase + u*16 + col)
    const int qbase = qp2 * 128 + w * 32;
    bf16x8 qh[2][2], ql[2][2];
#pragma unroll
    for (int u = 0; u < 2; u++) {
        const ushort_t* qp = Qhi + kbase + (size_t)(qbase + u * 16 + col) * D_HEAD;
        qh[u][0] = *(const bf16x8*)(qp + quad * 8);
        qh[u][1] = *(const bf16x8*)(qp + 32 + quad * 8);
        if (HILO) {
            const ushort_t* lp = Qlo + kbase + (size_t)(qbase + u * 16 + col) * D_HEAD;
            ql[u][0] = *(const bf16x8*)(lp + quad * 8);
            ql[u][1] = *(const bf16x8*)(lp + 32 + quad * 8);
        }
    }

    f32x4 acco[2][4] = {};
    float mrun[2] = {-1e30f, -1e30f}, lrun[2] = {0.f, 0.f};
    const float inv_temper = 0.04419417382415922f;  // 1/sqrt(512)

    const int tbeg = split * (SEQ / 2);
    const int tend = tbeg + SEQ / 2;

    // T14 stage registers; prologue: tile0 -> buf0, then issue tile1 loads
    uint4 rK0, rK1, rL0, rL1, rV0, rV1;
    {
        const int t0 = tbeg;
        rK0 = *(const uint4*)(Khi + kbase + (size_t)(t0 + srow0) * D_HEAD + sch);
        rK1 = *(const uint4*)(Khi + kbase + (size_t)(t0 + srow1) * D_HEAD + sch);
        if (HILO) {
            rL0 = *(const uint4*)(Klo + kbase + (size_t)(t0 + srow0) * D_HEAD + sch);
            rL1 = *(const uint4*)(Klo + kbase + (size_t)(t0 + srow1) * D_HEAD + sch);
        }
        rV0 = *(const uint4*)(Vt + vbase + (size_t)srow0 * SEQ + t0 + sch);
        rV1 = *(const uint4*)(Vt + vbase + (size_t)srow1 * SEQ + t0 + sch);
        *(uint4*)(&Kh[0][srow0][sch]) = rK0;
        *(uint4*)(&Kh[0][srow1][sch]) = rK1;
        if (HILO) {
            *(uint4*)(&Kl[0][srow0][sch]) = rL0;
            *(uint4*)(&Kl[0][srow1][sch]) = rL1;
        }
        *(uint4*)(&Vs[0][srow0][sch]) = rV0;
        *(uint4*)(&Vs[0][srow1][sch]) = rV1;
    }
    __syncthreads();
    if (tbeg + 64 < tend) {
        const int tn = tbeg + 64;
        rK0 = *(const uint4*)(Khi + kbase + (size_t)(tn + srow0) * D_HEAD + sch);
        rK1 = *(const uint4*)(Khi + kbase + (size_t)(tn + srow1) * D_HEAD + sch);
        if (HILO) {
            rL0 = *(const uint4*)(Klo + kbase + (size_t)(tn + srow0) * D_HEAD + sch);
            rL1 = *(const uint4*)(Klo + kbase + (size_t)(tn + srow1) * D_HEAD + sch);
        }
        rV0 = *(const uint4*)(Vt + vbase + (size_t)srow0 * SEQ + tn + sch);
        rV1 = *(const uint4*)(Vt + vbase + (size_t)srow1 * SEQ + tn + sch);
    }

    int cur = 0;
    for (int t0 = tbeg; t0 < tend; t0 += 64) {
        // ---- S^T tiles from buf[cur]
        float sc[2][4][4];
#pragma unroll
        for (int nt = 0; nt < 4; nt++) {
            bf16x8 kh0 = *(const bf16x8*)(&Kh[cur][nt * 16 + col][quad * 8]);
            bf16x8 kh1 = *(const bf16x8*)(&Kh[cur][nt * 16 + col][32 + quad * 8]);
            f32x4 s0 = {}, s1 = {};
            s0 = __builtin_amdgcn_mfma_f32_16x16x32_bf16(kh0, qh[0][0], s0, 0, 0, 0);
            s0 = __builtin_amdgcn_mfma_f32_16x16x32_bf16(kh1, qh[0][1], s0, 0, 0, 0);
            s1 = __builtin_amdgcn_mfma_f32_16x16x32_bf16(kh0, qh[1][0], s1, 0, 0, 0);
            s1 = __builtin_amdgcn_mfma_f32_16x16x32_bf16(kh1, qh[1][1], s1, 0, 0, 0);
            if (HILO) {
                bf16x8 kl0 = *(const bf16x8*)(&Kl[cur][nt * 16 + col][quad * 8]);
                bf16x8 kl1 = *(const bf16x8*)(&Kl[cur][nt * 16 + col][32 + quad * 8]);
                s0 = __builtin_amdgcn_mfma_f32_16x16x32_bf16(kl0, qh[0][0], s0, 0, 0, 0);
                s0 = __builtin_amdgcn_mfma_f32_16x16x32_bf16(kl1, qh[0][1], s0, 0, 0, 0);
                s0 = __builtin_amdgcn_mfma_f32_16x16x32_bf16(kh0, ql[0][0], s0, 0, 0, 0);
                s0 = __builtin_amdgcn_mfma_f32_16x16x32_bf16(kh1, ql[0][1], s0, 0, 0, 0);
                s1 = __builtin_amdgcn_mfma_f32_16x16x32_bf16(kl0, qh[1][0], s1, 0, 0, 0);
                s1 = __builtin_amdgcn_mfma_f32_16x16x32_bf16(kl1, qh[1][1], s1, 0, 0, 0);
                s1 = __builtin_amdgcn_mfma_f32_16x16x32_bf16(kh0, ql[1][0], s1, 0, 0, 0);
                s1 = __builtin_amdgcn_mfma_f32_16x16x32_bf16(kh1, ql[1][1], s1, 0, 0, 0);
            }
#pragma unroll
            for (int r = 0; r < 4; r++) {
                sc[0][nt][r] = s0[r] * inv_temper;
                sc[1][nt][r] = s1[r] * inv_temper;
            }
        }

        // ---- softmax per subtile (T13 defer-max, THR=8), parallel-u
#pragma unroll
        for (int u = 0; u < 2; u++) {
            float tmax = sc[u][0][0];
#pragma unroll
            for (int nt = 0; nt < 4; nt++)
#pragma unroll
                for (int r = 0; r < 4; r++) tmax = fmaxf(tmax, sc[u][nt][r]);
            tmax = fmaxf(tmax, __shfl_xor(tmax, 16, 64));
            tmax = fmaxf(tmax, __shfl_xor(tmax, 32, 64));

            if (!__all(tmax - mrun[u] <= 8.f)) {
                float mn = fmaxf(mrun[u], tmax);
                float alpha = __expf(mrun[u] - mn);
                mrun[u] = mn;
                lrun[u] *= alpha;
#pragma unroll
                for (int nt = 0; nt < 4; nt++)
#pragma unroll
                    for (int r = 0; r < 4; r++) acco[u][nt][r] *= alpha;
            }
            const float mn = mrun[u];
            float tsum = 0.f;
#pragma unroll
            for (int nt = 0; nt < 4; nt++) {
                float p0 = __expf(sc[u][nt][0] - mn);
                float p1 = __expf(sc[u][nt][1] - mn);
                float p2 = __expf(sc[u][nt][2] - mn);
                float p3 = __expf(sc[u][nt][3] - mn);
                tsum += (p0 + p1) + (p2 + p3);
                ull_t pk = (ull_t)f2bf(p0) | ((ull_t)f2bf(p1) << 16)
                         | ((ull_t)f2bf(p2) << 32) | ((ull_t)f2bf(p3) << 48);
                *(ull_t*)(&Pl[w][u][col][nt * 16 + quad * 4]) = pk;
            }
            tsum += __shfl_xor(tsum, 16, 64);
            tsum += __shfl_xor(tsum, 32, 64);
            lrun[u] += tsum;
        }

        __threadfence_block();   // order the typed-punned P round-trip

        // ---- PV from buf[cur]
        union { ulong2 uu; bf16x8 v; } pa[2][2];
#pragma unroll
        for (int u = 0; u < 2; u++) {
            pa[u][0].uu = *(const ulong2*)(&Pl[w][u][col][quad * 8]);
            pa[u][1].uu = *(const ulong2*)(&Pl[w][u][col][32 + quad * 8]);
        }
#pragma unroll
        for (int nt = 0; nt < 4; nt++) {
            bf16x8 bv0 = *(const bf16x8*)(&Vs[cur][nt * 16 + col][quad * 8]);
            bf16x8 bv1 = *(const bf16x8*)(&Vs[cur][nt * 16 + col][32 + quad * 8]);
            acco[0][nt] = __builtin_amdgcn_mfma_f32_16x16x32_bf16(bv0, pa[0][0].v, acco[0][nt], 0, 0, 0);
            acco[0][nt] = __builtin_amdgcn_mfma_f32_16x16x32_bf16(bv1, pa[0][1].v, acco[0][nt], 0, 0, 0);
            acco[1][nt] = __builtin_amdgcn_mfma_f32_16x16x32_bf16(bv0, pa[1][0].v, acco[1][nt], 0, 0, 0);
            acco[1][nt] = __builtin_amdgcn_mfma_f32_16x16x32_bf16(bv1, pa[1][1].v, acco[1][nt], 0, 0, 0);
        }

        // ---- stage tile t0+64 into buf[cur^1]; issue loads for t0+128
        if (t0 + 64 < tend) {
            *(uint4*)(&Kh[cur ^ 1][srow0][sch]) = rK0;
            *(uint4*)(&Kh[cur ^ 1][srow1][sch]) = rK1;
            if (HILO) {
                *(uint4*)(&Kl[cur ^ 1][srow0][sch]) = rL0;
                *(uint4*)(&Kl[cur ^ 1][srow1][sch]) = rL1;
            }
            *(uint4*)(&Vs[cur ^ 1][srow0][sch]) = rV0;
            *(uint4*)(&Vs[cur ^ 1][srow1][sch]) = rV1;
            if (t0 + 128 < tend) {
                const int tn = t0 + 128;
                rK0 = *(const uint4*)(Khi + kbase + (size_t)(tn + srow0) * D_HEAD + sch);
                rK1 = *(const uint4*)(Khi + kbase + (size_t)(tn + srow1) * D_HEAD + sch);
                if (HILO) {
                    rL0 = *(const uint4*)(Klo + kbase + (size_t)(tn + srow0) * D_HEAD + sch);
                    rL1 = *(const uint4*)(Klo + kbase + (size_t)(tn + srow1) * D_HEAD + sch);
                }
                rV0 = *(const uint4*)(Vt + vbase + (size_t)srow0 * SEQ + tn + sch);
                rV1 = *(const uint4*)(Vt + vbase + (size_t)srow1 * SEQ + tn + sch);
            }
        }
        __syncthreads();   // publishes buf[cur^1]; also closes reads of buf[cur]
        cur ^= 1;
    }

    // unnormalized partials + (m,l); combined in add_norm_combine_kernel
    float* dst = split ? P1 : P0;
#pragma unroll
    for (int u = 0; u < 2; u++) {
        const int qrow = qbase + u * 16 + col;
#pragma unroll
        for (int nt = 0; nt < 4; nt++)
            *(f32x4*)(&dst[((size_t)b * SEQ + qrow) * D_MODEL + h * D_HEAD
                           + nt * 16 + quad * 4]) = acco[u][nt];
        if (quad == 0)
            ML[((size_t)split * 32 + hb) * SEQ + qrow] = make_float2(mrun[u], lrun[u]);
    }
}

// ---------------------------------------------------------------- add + LN
// Wave-per-token LN (R9, validated): f32x4 loads, __shfl_xor reductions,
// zero barriers.
__device__ __forceinline__ float wave_sum_64(float v) {
#pragma unroll
    for (int off = 32; off > 0; off >>= 1) v += __shfl_xor(v, off, 64);
    return v;
}

__global__ void add_norm_kernel(const float* __restrict__ A,
                                const float* __restrict__ R,
                                const float* __restrict__ ga,
                                const float* __restrict__ gb,
                                float* __restrict__ Out,
                                ushort_t* __restrict__ OutBf) {
    int tok = blockIdx.x * 4 + (threadIdx.x >> 6);
    int lane = threadIdx.x & 63;
    size_t base = (size_t)tok * D_MODEL + lane * 8;
    f32x4 a0 = *(const f32x4*)(A + base);
    f32x4 a1 = *(const f32x4*)(A + base + 4);
    f32x4 r0 = *(const f32x4*)(R + base);
    f32x4 r1 = *(const f32x4*)(R + base + 4);
    f32x4 z0, z1;
#pragma unroll
    for (int t = 0; t < 4; t++) { z0[t] = a0[t] + r0[t]; z1[t] = a1[t] + r1[t]; }
    float s = (z0[0] + z0[1] + z0[2] + z0[3]) + (z1[0] + z1[1] + z1[2] + z1[3]);
    s = wave_sum_64(s);
    float mu = s * (1.f / (float)D_MODEL);
    float ss = 0.f;
#pragma unroll
    for (int t = 0; t < 4; t++) {
        float d0 = z0[t] - mu, d1 = z1[t] - mu;
        ss += d0 * d0 + d1 * d1;
    }
    ss = wave_sum_64(ss);
    float sigma = sqrtf(ss * (1.f / (float)(D_MODEL - 1)));
    float inv = 1.f / (sigma + LN_EPS);
    f32x4 g0 = *(const f32x4*)(ga + lane * 8);
    f32x4 g1 = *(const f32x4*)(ga + lane * 8 + 4);
    f32x4 h0 = *(const f32x4*)(gb + lane * 8);
    f32x4 h1 = *(const f32x4*)(gb + lane * 8 + 4);
    f32x4 o0, o1;
    bf16x8 pk;
#pragma unroll
    for (int t = 0; t < 4; t++) {
        o0[t] = (z0[t] - mu) * inv * g0[t] + h0[t];
        o1[t] = (z1[t] - mu) * inv * g1[t] + h1[t];
        pk[t] = (short)f2bf(o0[t]);
        pk[t + 4] = (short)f2bf(o1[t]);
    }
    *(f32x4*)(Out + base) = o0;
    *(f32x4*)(Out + base + 4) = o1;
    *(bf16x8*)(OutBf + base) = pk;
}

// Fuses the 2-way flash-decoding combine with residual-add + LN (ln1 path).
__global__ void add_norm_combine_kernel(const float* __restrict__ Pa,
                                        const float* __restrict__ Pb,
                                        const float2* __restrict__ ML,
                                        const float* __restrict__ R,
                                        const float* __restrict__ ga,
                                        const float* __restrict__ gb,
                                        float* __restrict__ Out,
                                        ushort_t* __restrict__ OutBf) {
    int tok = blockIdx.x * 4 + (threadIdx.x >> 6);
    int lane = threadIdx.x & 63;
    int b = tok >> 10, l = tok & 1023;
    int hb0 = (lane >> 3) * 4 + b;
    float2 u0 = ML[(size_t)hb0 * SEQ + l];
    float2 u1 = ML[(size_t)(32 + hb0) * SEQ + l];
    float M = fmaxf(u0.x, u1.x);
    float e0 = __expf(u0.x - M), e1 = __expf(u1.x - M);
    float sinv = 1.f / (e0 * u0.y + e1 * u1.y);
    float sa = e0 * sinv, sb = e1 * sinv;
    size_t base = (size_t)tok * D_MODEL + lane * 8;
    f32x4 pa0 = *(const f32x4*)(Pa + base);
    f32x4 pa1 = *(const f32x4*)(Pa + base + 4);
    f32x4 pb0 = *(const f32x4*)(Pb + base);
    f32x4 pb1 = *(const f32x4*)(Pb + base + 4);
    f32x4 r0 = *(const f32x4*)(R + base);
    f32x4 r1 = *(const f32x4*)(R + base + 4);
    f32x4 z0, z1;
#pragma unroll
    for (int t = 0; t < 4; t++) {
        z0[t] = pa0[t] * sa + pb0[t] * sb + r0[t];
        z1[t] = pa1[t] * sa + pb1[t] * sb + r1[t];
    }
    float s = (z0[0] + z0[1] + z0[2] + z0[3]) + (z1[0] + z1[1] + z1[2] + z1[3]);
    s = wave_sum_64(s);
    float mu = s * (1.f / (float)D_MODEL);
    float ss = 0.f;
#pragma unroll
    for (int t = 0; t < 4; t++) {
        float d0 = z0[t] - mu, d1 = z1[t] - mu;
        ss += d0 * d0 + d1 * d1;
    }
    ss = wave_sum_64(ss);
    float sigma = sqrtf(ss * (1.f / (float)(D_MODEL - 1)));
    float inv = 1.f / (sigma + LN_EPS);
    f32x4 g0 = *(const f32x4*)(ga + lane * 8);
    f32x4 g1 = *(const f32x4*)(ga + lane * 8 + 4);
    f32x4 h0 = *(const f32x4*)(gb + lane * 8);
    f32x4 h1 = *(const f32x4*)(gb + lane * 8 + 4);
    f32x4 o0, o1;
    bf16x8 pk;
#pragma unroll
    for (int t = 0; t < 4; t++) {
        o0[t] = (z0[t] - mu) * inv * g0[t] + h0[t];
        o1[t] = (z1[t] - mu) * inv * g1[t] + h1[t];
        pk[t] = (short)f2bf(o0[t]);
        pk[t + 4] = (short)f2bf(o1[t]);
    }
    *(f32x4*)(Out + base) = o0;
    *(f32x4*)(Out + base + 4) = o1;
    *(bf16x8*)(OutBf + base) = pk;
}

// ---------------------------------------------------------------- launch
extern "C" void kernel_launch(void* const* d_in, const int* in_sizes, int n_in,
                              void* d_out, int out_size, void* d_ws, size_t ws_size,
                              hipStream_t stream) {
    const float* x     = (const float*)d_in[0];
    const float* pe    = (const float*)d_in[1];
    const float* w_qs  = (const float*)d_in[2];
    const float* w_ks  = (const float*)d_in[3];
    const float* w_vs  = (const float*)d_in[4];
    const float* ln1_a = (const float*)d_in[5];
    const float* ln1_b = (const float*)d_in[6];
    const float* w1    = (const float*)d_in[7];
    const float* b1    = (const float*)d_in[8];
    const float* w2    = (const float*)d_in[9];
    const float* b2    = (const float*)d_in[10];
    const float* ln2_a = (const float*)d_in[11];
    const float* ln2_b = (const float*)d_in[12];
    float* out = (float*)d_out;

    const size_t NXD = (size_t)NTOK * D_MODEL;       // 2M elements
    char* p = (char*)d_ws;
    float*    X    = (float*)p;     p += NXD * 4;                 // 8 MB
    float*    Ob   = (float*)p;     p += NXD * 4;                 // 8 MB
    ushort_t* Xbf  = (ushort_t*)p;  p += NXD * 2;                 // 4 MB
    ushort_t* Xraw = (ushort_t*)p;  p += NXD * 2;                 // 4 MB  bf16(x)
    ushort_t* Qhi  = (ushort_t*)p;  p += NXD * 2;                 // 4 MB
    ushort_t* Qlo  = (ushort_t*)p;  p += NXD * 2;                 // 4 MB
    ushort_t* Khi  = (ushort_t*)p;  p += NXD * 2;                 // 4 MB
    ushort_t* Klo  = (ushort_t*)p;  p += NXD * 2;                 // 4 MB
    ushort_t* Vt   = (ushort_t*)p;  p += NXD * 2;                 // 4 MB
    ushort_t* Wqkv = (ushort_t*)p;  p += (size_t)N_LAYERS * 1536 * 512 * 2;  // 3 MB (hi)
    ushort_t* WqkvL= (ushort_t*)p;  p += (size_t)1536 * 512 * 2;  // 1.5 MB (lo, layer 0)
    ushort_t* W1b  = (ushort_t*)p;  p += (size_t)N_LAYERS * D_INNER * D_MODEL * 2;  // 2 MB
    ushort_t* W2b  = (ushort_t*)p;  p += (size_t)N_LAYERS * D_MODEL * D_INNER * 2;  // 2 MB
    float2*   ML   = (float2*)p;    /* 512 KB */
    // Aliases (stream-ordered safe): H = Qhi/Qlo (dead after attention);
    // PEW = Ob; attention partials: P0 = Ob, P1 = out (d_out).
    ushort_t* Hbf  = Qhi;
    float*    PEW  = Ob;

    prep_kernel<<<(PREP_TOTAL + 255) / 256, 256, 0, stream>>>(
        x, pe, w_qs, w_ks, w_vs, w1, w2, X, Xraw, Wqkv, WqkvL, W1b, W2b);

    for (int i = 0; i < N_LAYERS; i++) {
        if (i == 0) {
            gemm_hilo_kernel<<<dim3(1536 / 64, SEQ / 64), 256, 0, stream>>>(
                pe, Wqkv, WqkvL, PEW, SEQ, 1536, D_MODEL);
            gemm_kernel<0, 128, 64><<<dim3(1536 / 64, NTOK / 128), 256, 0, stream>>>(
                Xraw, Wqkv, nullptr, PEW, nullptr, nullptr,
                Qhi, Qlo, Khi, Klo, Vt, NTOK, 1536, D_MODEL);
            attention_kernel<true><<<512, 256, 0, stream>>>(
                Qhi, Qlo, Khi, Klo, Vt, Ob, out, ML);
        } else {
            gemm_kernel<0, 128, 64><<<dim3(1536 / 64, NTOK / 128), 256, 0, stream>>>(
                Xbf, Wqkv + (size_t)i * 1536 * 512, nullptr, nullptr, nullptr,
                nullptr, Qhi, Qlo, Khi, Klo, Vt, NTOK, 1536, D_MODEL);
            attention_kernel<false><<<512, 256, 0, stream>>>(
                Qhi, Qlo, Khi, Klo, Vt, Ob, out, ML);
        }

        add_norm_combine_kernel<<<NTOK / 4, 256, 0, stream>>>(
            Ob, out, ML, X, ln1_a + i * D_MODEL, ln1_b + i * D_MODEL, X, Xbf);

        // FFN1: M=4096, N=1024, K=512, bias+relu -> bf16 H (aliases Qhi/Qlo)
        gemm_kernel<1, 128, 64><<<dim3(D_INNER / 64, NTOK / 128), 256, 0, stream>>>(
            Xbf, W1b + (size_t)i * D_INNER * D_MODEL, b1 + (size_t)i * D_INNER,
            nullptr, nullptr, Hbf, nullptr, nullptr, nullptr, nullptr, nullptr,
            NTOK, D_INNER, D_MODEL);

        // FFN2: M=4096, N=512, K=1024, bias -> fp32 Ob (single-pass 64^2)
        gemm_kernel<2, 64, 64><<<dim3(D_MODEL / 64, NTOK / 64), 256, 0, stream>>>(
            Hbf, W2b + (size_t)i * D_MODEL * D_INNER, b2 + (size_t)i * D_MODEL,
            nullptr, Ob, nullptr, nullptr, nullptr, nullptr, nullptr, nullptr,
            NTOK, D_MODEL, D_INNER);

        float* dst = (i == N_LAYERS - 1) ? out : X;
        add_norm_kernel<<<NTOK / 4, 256, 0, stream>>>(
            Ob, X, ln2_a + i * D_MODEL, ln2_b + i * D_MODEL, dst, Xbf);
    }
}